// Round 2
// baseline (193.104 us; speedup 1.0000x reference)
//
#include <hip/hip_runtime.h>
#include <hip/hip_bf16.h>
#include <stdint.h>
#include <stddef.h>

#define B_  4
#define S_  2048
#define D_  1024
#define TB_ 128

typedef float v4f  __attribute__((ext_vector_type(4)));
typedef short s16x4 __attribute__((ext_vector_type(4)));
typedef short s16x8 __attribute__((ext_vector_type(8)));

// round-to-nearest-even f32 -> bf16 (bit pattern as ushort)
__device__ __forceinline__ unsigned short f2bf(float f) {
  union { float f; unsigned u; } x; x.f = f;
  unsigned u = x.u;
  unsigned r = (u + 0x7FFFu + ((u >> 16) & 1u)) >> 16;
  return (unsigned short)r;
}

// async global->LDS, 16B per lane; lds dest is wave-uniform base + lane*16
__device__ __forceinline__ void gld16(const void* g, void* l) {
  __builtin_amdgcn_global_load_lds(
      (const __attribute__((address_space(1))) unsigned int*)g,
      (__attribute__((address_space(3))) unsigned int*)l, 16, 0, 0);
}

// ---------------- gate: sigmoid(task_bias @ W + b), one wave per batch ----
__global__ __launch_bounds__(256) void gate_kernel(
    const float* __restrict__ tb, const float* __restrict__ W,
    const float* __restrict__ bias, float* __restrict__ gate) {
  int t = threadIdx.x;
  int b = t >> 6, l = t & 63;
  float s = tb[b * TB_ + l] * W[l] + tb[b * TB_ + 64 + l] * W[64 + l];
  #pragma unroll
  for (int off = 32; off > 0; off >>= 1) s += __shfl_down(s, off, 64);
  if (l == 0) gate[b] = 1.0f / (1.0f + __expf(-(s + bias[0])));
}

// ---------------- f32 -> bf16 bulk convert (vectorized) -------------------
__global__ __launch_bounds__(256) void cvt_bf16_kernel(
    const float* __restrict__ src, short* __restrict__ dst) {
  size_t g = (size_t)blockIdx.x * 256 + threadIdx.x;  // one float4 each
  v4f v = *(const v4f*)(src + g * 4);
  s16x4 o;
  o[0] = (short)f2bf(v[0]); o[1] = (short)f2bf(v[1]);
  o[2] = (short)f2bf(v[2]); o[3] = (short)f2bf(v[3]);
  *(s16x4*)(dst + g * 4) = o;
}

// ---------------- V [b][s][d] f32 -> V^T [b][d][s] bf16 (LDS tiled) -------
__global__ __launch_bounds__(256) void vT_kernel(
    const float* __restrict__ V, short* __restrict__ VT) {
  __shared__ float tile[64][65];
  int b = blockIdx.z;
  int s0 = blockIdx.x * 64, d0 = blockIdx.y * 64;
  int t = threadIdx.x;
  int tc = t & 63, tr4 = t >> 6;  // col 0..63, row-quad 0..3
  const float* src = V + ((size_t)b * S_ + s0) * D_ + d0;
  #pragma unroll
  for (int p = 0; p < 16; ++p) {
    int r = p * 4 + tr4;
    tile[r][tc] = src[(size_t)r * D_ + tc];
  }
  __syncthreads();
  short* dst = VT + ((size_t)b * D_ + d0) * S_ + s0;
  #pragma unroll
  for (int p = 0; p < 16; ++p) {
    int r = p * 4 + tr4;  // d-offset
    dst[(size_t)r * S_ + tc] = (short)f2bf(tile[tc][r]);
  }
}

// ---------------- QK^T GEMM: scores = gate * (Q K^T) / 32 -----------------
// 128x128 tile, 4 waves (2x2), each wave 64x64 = 4x4 frags of 16x16, BK=32.
__global__ __launch_bounds__(256) void qk_gemm(
    const short* __restrict__ Qb, const short* __restrict__ Kb,
    const float* __restrict__ gate, float* __restrict__ attn) {
  __shared__ __align__(16) short lA[128 * 32];
  __shared__ __align__(16) short lB[128 * 32];
  int b = blockIdx.z;
  int m0 = blockIdx.y * 128, n0 = blockIdx.x * 128;
  int t = threadIdx.x, w = t >> 6, l = t & 63;
  int wr = w >> 1, wc = w & 1;
  const short* Ab = Qb + (size_t)b * S_ * D_;
  const short* Bb = Kb + (size_t)b * S_ * D_;
  int sr = l >> 2;           // staging row within 16-row region
  int sc = (l & 3) * 8;      // staging col (bf16 elems)
  int fr = l & 15;           // fragment row/col
  int fk = (l >> 4) * 8;     // fragment k offset
  v4f acc[4][4];
  #pragma unroll
  for (int m = 0; m < 4; ++m)
    #pragma unroll
    for (int n = 0; n < 4; ++n)
      #pragma unroll
      for (int j = 0; j < 4; ++j) acc[m][n][j] = 0.0f;

  for (int k0 = 0; k0 < D_; k0 += 32) {
    #pragma unroll
    for (int i = 0; i < 2; ++i) {
      int reg = i * 4 + w;           // region 0..7 (16 rows each)
      int row = reg * 16 + sr;
      gld16(Ab + (size_t)(m0 + row) * D_ + k0 + sc, &lA[reg * 512]);
      gld16(Bb + (size_t)(n0 + row) * D_ + k0 + sc, &lB[reg * 512]);
    }
    __syncthreads();
    s16x8 af[4], bfr[4];
    #pragma unroll
    for (int m = 0; m < 4; ++m)
      af[m] = *(const s16x8*)&lA[(wr * 64 + m * 16 + fr) * 32 + fk];
    #pragma unroll
    for (int n = 0; n < 4; ++n)
      bfr[n] = *(const s16x8*)&lB[(wc * 64 + n * 16 + fr) * 32 + fk];
    #pragma unroll
    for (int m = 0; m < 4; ++m)
      #pragma unroll
      for (int n = 0; n < 4; ++n)
        acc[m][n] = __builtin_amdgcn_mfma_f32_16x16x32_bf16(af[m], bfr[n], acc[m][n], 0, 0, 0);
    __syncthreads();
  }
  float g = gate[b] * 0.03125f;  // 1/sqrt(1024)
  float* out = attn + (size_t)b * S_ * S_;
  #pragma unroll
  for (int m = 0; m < 4; ++m)
    #pragma unroll
    for (int n = 0; n < 4; ++n) {
      int row = m0 + wr * 64 + m * 16 + (l >> 4) * 4;
      int col = n0 + wc * 64 + n * 16 + (l & 15);
      #pragma unroll
      for (int j = 0; j < 4; ++j)
        out[(size_t)(row + j) * S_ + col] = acc[m][n][j] * g;
    }
}

// ---------------- row softmax in-place: 8192 rows x 2048 ------------------
__global__ __launch_bounds__(256) void softmax_kernel(float* __restrict__ attn) {
  size_t row = blockIdx.x;
  float* p = attn + row * S_;
  int t = threadIdx.x;
  v4f v0 = *(const v4f*)(p + t * 8);
  v4f v1 = *(const v4f*)(p + t * 8 + 4);
  float m = fmaxf(fmaxf(fmaxf(v0[0], v0[1]), fmaxf(v0[2], v0[3])),
                  fmaxf(fmaxf(v1[0], v1[1]), fmaxf(v1[2], v1[3])));
  #pragma unroll
  for (int off = 32; off > 0; off >>= 1) m = fmaxf(m, __shfl_xor(m, off, 64));
  __shared__ float rm[4], rs[4];
  if ((t & 63) == 0) rm[t >> 6] = m;
  __syncthreads();
  m = fmaxf(fmaxf(rm[0], rm[1]), fmaxf(rm[2], rm[3]));
  float e[8]; float sum = 0.0f;
  #pragma unroll
  for (int j = 0; j < 4; ++j) { e[j] = __expf(v0[j] - m); sum += e[j]; }
  #pragma unroll
  for (int j = 0; j < 4; ++j) { e[4 + j] = __expf(v1[j] - m); sum += e[4 + j]; }
  #pragma unroll
  for (int off = 32; off > 0; off >>= 1) sum += __shfl_xor(sum, off, 64);
  if ((t & 63) == 0) rs[t >> 6] = sum;
  __syncthreads();
  sum = rs[0] + rs[1] + rs[2] + rs[3];
  float inv = 1.0f / sum;
  #pragma unroll
  for (int j = 0; j < 4; ++j) v0[j] = e[j] * inv;
  #pragma unroll
  for (int j = 0; j < 4; ++j) v1[j] = e[4 + j] * inv;
  *(v4f*)(p + t * 8) = v0;
  *(v4f*)(p + t * 8 + 4) = v1;
}

// ---------------- PV GEMM: out = attn(f32->bf16) @ V, B from V^T ----------
__global__ __launch_bounds__(256) void pv_gemm(
    const float* __restrict__ attn, const short* __restrict__ VTb,
    float* __restrict__ out) {
  __shared__ __align__(16) short lA[128 * 32];
  __shared__ __align__(16) short lB[128 * 32];
  int b = blockIdx.z;
  int m0 = blockIdx.y * 128, n0 = blockIdx.x * 128;  // n over D_
  int t = threadIdx.x, w = t >> 6, l = t & 63;
  int wr = w >> 1, wc = w & 1;
  const float* Ab = attn + (size_t)b * S_ * S_;
  const short* Bb = VTb + (size_t)b * D_ * S_;
  int sr = l >> 2, sc = (l & 3) * 8;
  int ar = t >> 3;             // A-stage row base (within 32-row chunk)
  int ac = (t & 7) * 4;        // A-stage col
  int fr = l & 15, fk = (l >> 4) * 8;
  v4f acc[4][4];
  #pragma unroll
  for (int m = 0; m < 4; ++m)
    #pragma unroll
    for (int n = 0; n < 4; ++n)
      #pragma unroll
      for (int j = 0; j < 4; ++j) acc[m][n][j] = 0.0f;

  for (int k0 = 0; k0 < S_; k0 += 32) {
    #pragma unroll
    for (int i = 0; i < 2; ++i) {
      int reg = i * 4 + w;
      int row = reg * 16 + sr;  // d-offset (output col)
      gld16(Bb + (size_t)(n0 + row) * S_ + k0 + sc, &lB[reg * 512]);
    }
    #pragma unroll
    for (int i = 0; i < 4; ++i) {
      int r = i * 32 + ar;
      v4f v = *(const v4f*)&Ab[(size_t)(m0 + r) * S_ + k0 + ac];
      s16x4 o;
      o[0] = (short)f2bf(v[0]); o[1] = (short)f2bf(v[1]);
      o[2] = (short)f2bf(v[2]); o[3] = (short)f2bf(v[3]);
      *(s16x4*)&lA[r * 32 + ac] = o;
    }
    __syncthreads();
    s16x8 af[4], bfr[4];
    #pragma unroll
    for (int m = 0; m < 4; ++m)
      af[m] = *(const s16x8*)&lA[(wr * 64 + m * 16 + fr) * 32 + fk];
    #pragma unroll
    for (int n = 0; n < 4; ++n)
      bfr[n] = *(const s16x8*)&lB[(wc * 64 + n * 16 + fr) * 32 + fk];
    #pragma unroll
    for (int m = 0; m < 4; ++m)
      #pragma unroll
      for (int n = 0; n < 4; ++n)
        acc[m][n] = __builtin_amdgcn_mfma_f32_16x16x32_bf16(af[m], bfr[n], acc[m][n], 0, 0, 0);
    __syncthreads();
  }
  float* ob = out + (size_t)b * S_ * D_;
  #pragma unroll
  for (int m = 0; m < 4; ++m)
    #pragma unroll
    for (int n = 0; n < 4; ++n) {
      int row = m0 + wr * 64 + m * 16 + (l >> 4) * 4;
      int col = n0 + wc * 64 + n * 16 + (l & 15);
      #pragma unroll
      for (int j = 0; j < 4; ++j)
        ob[(size_t)(row + j) * D_ + col] = acc[m][n][j];
    }
}

extern "C" void kernel_launch(void* const* d_in, const int* in_sizes, int n_in,
                              void* d_out, int out_size, void* d_ws, size_t ws_size,
                              hipStream_t stream) {
  (void)in_sizes; (void)n_in; (void)out_size; (void)ws_size;
  const float* Q  = (const float*)d_in[0];
  const float* K  = (const float*)d_in[1];
  const float* V  = (const float*)d_in[2];
  const float* tb = (const float*)d_in[3];
  const float* W  = (const float*)d_in[4];
  const float* bias = (const float*)d_in[5];

  float* out  = (float*)d_out;                       // [4,2048,1024]
  float* attn = out + (size_t)B_ * S_ * D_;          // [4,2048,2048]

  char* ws = (char*)d_ws;
  float* gate = (float*)ws;                          // 4 floats
  short* Qb = (short*)(ws + 256);                    // bf16 [4][2048][1024]
  short* Kb = Qb + (size_t)B_ * S_ * D_;             // bf16 [4][2048][1024]
  short* VT = Kb + (size_t)B_ * S_ * D_;             // bf16 [4][1024][2048]

  gate_kernel<<<1, 256, 0, stream>>>(tb, W, bias, gate);
  cvt_bf16_kernel<<<8192, 256, 0, stream>>>(Q, Qb);
  cvt_bf16_kernel<<<8192, 256, 0, stream>>>(K, Kb);
  vT_kernel<<<dim3(32, 16, 4), 256, 0, stream>>>(V, VT);
  qk_gemm<<<dim3(16, 16, 4), 256, 0, stream>>>(Qb, Kb, gate, attn);
  softmax_kernel<<<8192, 256, 0, stream>>>(attn);
  pv_gemm<<<dim3(8, 16, 4), 256, 0, stream>>>(attn, VT, out);
}

// Round 3
// 163.727 us; speedup vs baseline: 1.1794x; 1.1794x over previous
//
#include <hip/hip_runtime.h>
#include <hip/hip_bf16.h>
#include <stdint.h>
#include <stddef.h>

#define B_  4
#define S_  2048
#define D_  1024
#define TB_ 128

typedef float v4f  __attribute__((ext_vector_type(4)));
typedef short s16x4 __attribute__((ext_vector_type(4)));
typedef short s16x8 __attribute__((ext_vector_type(8)));

// round-to-nearest-even f32 -> bf16 (bit pattern as ushort)
__device__ __forceinline__ unsigned short f2bf(float f) {
  union { float f; unsigned u; } x; x.f = f;
  unsigned u = x.u;
  unsigned r = (u + 0x7FFFu + ((u >> 16) & 1u)) >> 16;
  return (unsigned short)r;
}

// async global->LDS, 16B per lane; lds dest is wave-uniform base + lane*16
__device__ __forceinline__ void gld16(const void* g, void* l) {
  __builtin_amdgcn_global_load_lds(
      (const __attribute__((address_space(1))) unsigned int*)g,
      (__attribute__((address_space(3))) unsigned int*)l, 16, 0, 0);
}

// ---------------- gate: sigmoid(task_bias @ W + b), one wave per batch ----
__global__ __launch_bounds__(256) void gate_kernel(
    const float* __restrict__ tb, const float* __restrict__ W,
    const float* __restrict__ bias, float* __restrict__ gate) {
  int t = threadIdx.x;
  int b = t >> 6, l = t & 63;
  float s = tb[b * TB_ + l] * W[l] + tb[b * TB_ + 64 + l] * W[64 + l];
  #pragma unroll
  for (int off = 32; off > 0; off >>= 1) s += __shfl_down(s, off, 64);
  if (l == 0) gate[b] = 1.0f / (1.0f + __expf(-(s + bias[0])));
}

// ---------------- f32 -> bf16 bulk convert (vectorized) -------------------
__global__ __launch_bounds__(256) void cvt_bf16_kernel(
    const float* __restrict__ src, short* __restrict__ dst) {
  size_t g = (size_t)blockIdx.x * 256 + threadIdx.x;  // one float4 each
  v4f v = *(const v4f*)(src + g * 4);
  s16x4 o;
  o[0] = (short)f2bf(v[0]); o[1] = (short)f2bf(v[1]);
  o[2] = (short)f2bf(v[2]); o[3] = (short)f2bf(v[3]);
  *(s16x4*)(dst + g * 4) = o;
}

// ---------------- V [b][s][d] f32 -> V^T [b][d][s] bf16 (LDS tiled) -------
__global__ __launch_bounds__(256) void vT_kernel(
    const float* __restrict__ V, short* __restrict__ VT) {
  __shared__ float tile[64][65];
  int b = blockIdx.z;
  int s0 = blockIdx.x * 64, d0 = blockIdx.y * 64;
  int t = threadIdx.x;
  int tc = t & 63, tr4 = t >> 6;  // col 0..63, row-quad 0..3
  const float* src = V + ((size_t)b * S_ + s0) * D_ + d0;
  #pragma unroll
  for (int p = 0; p < 16; ++p) {
    int r = p * 4 + tr4;
    tile[r][tc] = src[(size_t)r * D_ + tc];
  }
  __syncthreads();
  short* dst = VT + ((size_t)b * D_ + d0) * S_ + s0;
  #pragma unroll
  for (int p = 0; p < 16; ++p) {
    int r = p * 4 + tr4;  // d-offset
    dst[(size_t)r * S_ + tc] = (short)f2bf(tile[tc][r]);
  }
}

// ---------------- QK^T GEMM: scores = gate * (Q K^T) / 32 -----------------
// 128x128 tile, 4 waves (2x2), each wave 64x64 = 4x4 frags of 16x16, BK=32.
// 1D grid (1024 blocks), XCD-chunked swizzle: each XCD gets 128 contiguous
// tiles = half a batch (8 m-tiles x all 16 n-tiles) -> K-panel ~resident.
__global__ __launch_bounds__(256) void qk_gemm(
    const short* __restrict__ Qb, const short* __restrict__ Kb,
    const float* __restrict__ gate, float* __restrict__ attn) {
  __shared__ __align__(16) short lA[128 * 32];
  __shared__ __align__(16) short lB[128 * 32];
  int wg = blockIdx.x;
  int swz = (wg & 7) * 128 + (wg >> 3);   // 1024 % 8 == 0 -> bijective
  int b = swz >> 8;
  int rem = swz & 255;
  int m0 = (rem >> 4) * 128, n0 = (rem & 15) * 128;
  int t = threadIdx.x, w = t >> 6, l = t & 63;
  int wr = w >> 1, wc = w & 1;
  const short* Ab = Qb + (size_t)b * S_ * D_;
  const short* Bb = Kb + (size_t)b * S_ * D_;
  int sr = l >> 2;           // staging row within 16-row region
  int sc = (l & 3) * 8;      // staging col (bf16 elems)
  int fr = l & 15;           // fragment row/col
  int fk = (l >> 4) * 8;     // fragment k offset
  v4f acc[4][4];
  #pragma unroll
  for (int m = 0; m < 4; ++m)
    #pragma unroll
    for (int n = 0; n < 4; ++n)
      #pragma unroll
      for (int j = 0; j < 4; ++j) acc[m][n][j] = 0.0f;

  for (int k0 = 0; k0 < D_; k0 += 32) {
    #pragma unroll
    for (int i = 0; i < 2; ++i) {
      int reg = i * 4 + w;           // region 0..7 (16 rows each)
      int row = reg * 16 + sr;
      gld16(Ab + (size_t)(m0 + row) * D_ + k0 + sc, &lA[reg * 512]);
      gld16(Bb + (size_t)(n0 + row) * D_ + k0 + sc, &lB[reg * 512]);
    }
    __syncthreads();
    s16x8 af[4], bfr[4];
    #pragma unroll
    for (int m = 0; m < 4; ++m)
      af[m] = *(const s16x8*)&lA[(wr * 64 + m * 16 + fr) * 32 + fk];
    #pragma unroll
    for (int n = 0; n < 4; ++n)
      bfr[n] = *(const s16x8*)&lB[(wc * 64 + n * 16 + fr) * 32 + fk];
    #pragma unroll
    for (int m = 0; m < 4; ++m)
      #pragma unroll
      for (int n = 0; n < 4; ++n)
        acc[m][n] = __builtin_amdgcn_mfma_f32_16x16x32_bf16(af[m], bfr[n], acc[m][n], 0, 0, 0);
    __syncthreads();
  }
  float g = gate[b] * 0.03125f;  // 1/sqrt(1024)
  float* out = attn + (size_t)b * S_ * S_;
  #pragma unroll
  for (int m = 0; m < 4; ++m)
    #pragma unroll
    for (int n = 0; n < 4; ++n) {
      int row = m0 + wr * 64 + m * 16 + (l >> 4) * 4;
      int col = n0 + wc * 64 + n * 16 + (l & 15);
      #pragma unroll
      for (int j = 0; j < 4; ++j)
        out[(size_t)(row + j) * S_ + col] = acc[m][n][j] * g;
    }
}

// ---------------- row softmax: f32 in-place + bf16 copy for PV ------------
__global__ __launch_bounds__(256) void softmax_kernel(
    float* __restrict__ attn, short* __restrict__ attnb) {
  size_t row = blockIdx.x;
  float* p = attn + row * S_;
  int t = threadIdx.x;
  v4f v0 = *(const v4f*)(p + t * 8);
  v4f v1 = *(const v4f*)(p + t * 8 + 4);
  float m = fmaxf(fmaxf(fmaxf(v0[0], v0[1]), fmaxf(v0[2], v0[3])),
                  fmaxf(fmaxf(v1[0], v1[1]), fmaxf(v1[2], v1[3])));
  #pragma unroll
  for (int off = 32; off > 0; off >>= 1) m = fmaxf(m, __shfl_xor(m, off, 64));
  __shared__ float rm[4], rs[4];
  if ((t & 63) == 0) rm[t >> 6] = m;
  __syncthreads();
  m = fmaxf(fmaxf(rm[0], rm[1]), fmaxf(rm[2], rm[3]));
  float e[8]; float sum = 0.0f;
  #pragma unroll
  for (int j = 0; j < 4; ++j) { e[j] = __expf(v0[j] - m); sum += e[j]; }
  #pragma unroll
  for (int j = 0; j < 4; ++j) { e[4 + j] = __expf(v1[j] - m); sum += e[4 + j]; }
  #pragma unroll
  for (int off = 32; off > 0; off >>= 1) sum += __shfl_xor(sum, off, 64);
  if ((t & 63) == 0) rs[t >> 6] = sum;
  __syncthreads();
  sum = rs[0] + rs[1] + rs[2] + rs[3];
  float inv = 1.0f / sum;
  #pragma unroll
  for (int j = 0; j < 4; ++j) v0[j] = e[j] * inv;
  #pragma unroll
  for (int j = 0; j < 4; ++j) v1[j] = e[4 + j] * inv;
  *(v4f*)(p + t * 8) = v0;
  *(v4f*)(p + t * 8 + 4) = v1;
  s16x8 ob;
  ob[0] = (short)f2bf(v0[0]); ob[1] = (short)f2bf(v0[1]);
  ob[2] = (short)f2bf(v0[2]); ob[3] = (short)f2bf(v0[3]);
  ob[4] = (short)f2bf(v1[0]); ob[5] = (short)f2bf(v1[1]);
  ob[6] = (short)f2bf(v1[2]); ob[7] = (short)f2bf(v1[3]);
  *(s16x8*)(attnb + row * S_ + t * 8) = ob;
}

// ---------------- PV GEMM: out = Pb(bf16) @ V, B from V^T, pure gld16 -----
// Same verified structure as qk_gemm; K extent = S_ (64 iters).
// 1D grid (512 blocks), XCD-chunked: each XCD = half a batch (8m x 8n).
__global__ __launch_bounds__(256) void pv_gemm(
    const short* __restrict__ Pb, const short* __restrict__ VTb,
    float* __restrict__ out) {
  __shared__ __align__(16) short lA[128 * 32];
  __shared__ __align__(16) short lB[128 * 32];
  int wg = blockIdx.x;
  int swz = (wg & 7) * 64 + (wg >> 3);    // 512 % 8 == 0 -> bijective
  int b = swz >> 7;
  int rem = swz & 127;
  int m0 = (rem >> 3) * 128, n0 = (rem & 7) * 128;  // n over D_
  int t = threadIdx.x, w = t >> 6, l = t & 63;
  int wr = w >> 1, wc = w & 1;
  const short* Ab = Pb + (size_t)b * S_ * S_;
  const short* Bb = VTb + (size_t)b * D_ * S_;
  int sr = l >> 2, sc = (l & 3) * 8;
  int fr = l & 15, fk = (l >> 4) * 8;
  v4f acc[4][4];
  #pragma unroll
  for (int m = 0; m < 4; ++m)
    #pragma unroll
    for (int n = 0; n < 4; ++n)
      #pragma unroll
      for (int j = 0; j < 4; ++j) acc[m][n][j] = 0.0f;

  for (int k0 = 0; k0 < S_; k0 += 32) {
    #pragma unroll
    for (int i = 0; i < 2; ++i) {
      int reg = i * 4 + w;
      int row = reg * 16 + sr;
      gld16(Ab + (size_t)(m0 + row) * S_ + k0 + sc, &lA[reg * 512]);
      gld16(Bb + (size_t)(n0 + row) * S_ + k0 + sc, &lB[reg * 512]);
    }
    __syncthreads();
    s16x8 af[4], bfr[4];
    #pragma unroll
    for (int m = 0; m < 4; ++m)
      af[m] = *(const s16x8*)&lA[(wr * 64 + m * 16 + fr) * 32 + fk];
    #pragma unroll
    for (int n = 0; n < 4; ++n)
      bfr[n] = *(const s16x8*)&lB[(wc * 64 + n * 16 + fr) * 32 + fk];
    #pragma unroll
    for (int m = 0; m < 4; ++m)
      #pragma unroll
      for (int n = 0; n < 4; ++n)
        acc[m][n] = __builtin_amdgcn_mfma_f32_16x16x32_bf16(af[m], bfr[n], acc[m][n], 0, 0, 0);
    __syncthreads();
  }
  float* ob = out + (size_t)b * S_ * D_;
  #pragma unroll
  for (int m = 0; m < 4; ++m)
    #pragma unroll
    for (int n = 0; n < 4; ++n) {
      int row = m0 + wr * 64 + m * 16 + (l >> 4) * 4;
      int col = n0 + wc * 64 + n * 16 + (l & 15);
      #pragma unroll
      for (int j = 0; j < 4; ++j)
        ob[(size_t)(row + j) * D_ + col] = acc[m][n][j];
    }
}

extern "C" void kernel_launch(void* const* d_in, const int* in_sizes, int n_in,
                              void* d_out, int out_size, void* d_ws, size_t ws_size,
                              hipStream_t stream) {
  (void)in_sizes; (void)n_in; (void)out_size; (void)ws_size;
  const float* Q  = (const float*)d_in[0];
  const float* K  = (const float*)d_in[1];
  const float* V  = (const float*)d_in[2];
  const float* tb = (const float*)d_in[3];
  const float* W  = (const float*)d_in[4];
  const float* bias = (const float*)d_in[5];

  float* out  = (float*)d_out;                       // [4,2048,1024]
  float* attn = out + (size_t)B_ * S_ * D_;          // [4,2048,2048]

  char* ws = (char*)d_ws;
  float* gate = (float*)ws;                          // 4 floats
  short* Qb = (short*)(ws + 256);                    // bf16 [4][2048][1024] (16 MB)
  short* Kb = Qb + (size_t)B_ * S_ * D_;             // bf16 [4][2048][1024] (16 MB)
  short* VT = Kb + (size_t)B_ * S_ * D_;             // bf16 [4][1024][2048] (16 MB)
  // After qk_gemm, Qb/Kb are dead; softmax reuses their 32 MB for bf16 P.
  short* attnb = Qb;                                 // bf16 [4][2048][2048] (32 MB)

  gate_kernel<<<1, 256, 0, stream>>>(tb, W, bias, gate);
  cvt_bf16_kernel<<<8192, 256, 0, stream>>>(Q, Qb);
  cvt_bf16_kernel<<<8192, 256, 0, stream>>>(K, Kb);
  vT_kernel<<<dim3(32, 16, 4), 256, 0, stream>>>(V, VT);
  qk_gemm<<<1024, 256, 0, stream>>>(Qb, Kb, gate, attn);
  softmax_kernel<<<8192, 256, 0, stream>>>(attn, attnb);
  pv_gemm<<<512, 256, 0, stream>>>(attnb, VT, out);
}

// Round 5
// 140.366 us; speedup vs baseline: 1.3757x; 1.1664x over previous
//
#include <hip/hip_runtime.h>
#include <hip/hip_bf16.h>
#include <stdint.h>
#include <stddef.h>

#define B_  4
#define S_  2048
#define D_  1024
#define TB_ 128

typedef float v4f  __attribute__((ext_vector_type(4)));
typedef short s16x4 __attribute__((ext_vector_type(4)));
typedef short s16x8 __attribute__((ext_vector_type(8)));

#define WAITV(n) asm volatile("s_waitcnt vmcnt(" #n ")" ::: "memory")

__device__ __forceinline__ unsigned short f2bf(float f) {
  union { float f; unsigned u; } x; x.f = f;
  unsigned u = x.u;
  unsigned r = (u + 0x7FFFu + ((u >> 16) & 1u)) >> 16;
  return (unsigned short)r;
}

__device__ __forceinline__ void gld16(const void* g, void* l) {
  __builtin_amdgcn_global_load_lds(
      (const __attribute__((address_space(1))) unsigned int*)g,
      (__attribute__((address_space(3))) unsigned int*)l, 16, 0, 0);
}

// full sync: mem-clobber fences flank a raw s_barrier (no vmcnt(0) drain),
// sched_barrier(0) pins instruction motion (rule #18).
__device__ __forceinline__ void barrier_sync() {
  asm volatile("" ::: "memory");
  __builtin_amdgcn_s_barrier();
  asm volatile("" ::: "memory");
  __builtin_amdgcn_sched_barrier(0);
}

// ---------------- gate ----------------------------------------------------
__global__ __launch_bounds__(256) void gate_kernel(
    const float* __restrict__ tb, const float* __restrict__ W,
    const float* __restrict__ bias, float* __restrict__ gate) {
  int t = threadIdx.x;
  int b = t >> 6, l = t & 63;
  float s = tb[b * TB_ + l] * W[l] + tb[b * TB_ + 64 + l] * W[64 + l];
  #pragma unroll
  for (int off = 32; off > 0; off >>= 1) s += __shfl_down(s, off, 64);
  if (l == 0) gate[b] = 1.0f / (1.0f + __expf(-(s + bias[0])));
}

// ---------------- f32 -> bf16 bulk convert --------------------------------
__global__ __launch_bounds__(256) void cvt_bf16_kernel(
    const float* __restrict__ src, short* __restrict__ dst) {
  size_t g = (size_t)blockIdx.x * 256 + threadIdx.x;
  v4f v = *(const v4f*)(src + g * 4);
  s16x4 o;
  o[0] = (short)f2bf(v[0]); o[1] = (short)f2bf(v[1]);
  o[2] = (short)f2bf(v[2]); o[3] = (short)f2bf(v[3]);
  *(s16x4*)(dst + g * 4) = o;
}

// ---------------- V [b][s][d] f32 -> V^T [b][d][s] bf16 -------------------
__global__ __launch_bounds__(256) void vT_kernel(
    const float* __restrict__ V, short* __restrict__ VT) {
  __shared__ float tile[64][65];
  int b = blockIdx.z;
  int s0 = blockIdx.x * 64, d0 = blockIdx.y * 64;
  int t = threadIdx.x;
  int tc = t & 63, tr4 = t >> 6;
  const float* src = V + ((size_t)b * S_ + s0) * D_ + d0;
  #pragma unroll
  for (int p = 0; p < 16; ++p) {
    int r = p * 4 + tr4;
    tile[r][tc] = src[(size_t)r * D_ + tc];
  }
  __syncthreads();
  short* dst = VT + ((size_t)b * D_ + d0) * S_ + s0;
  #pragma unroll
  for (int p = 0; p < 16; ++p) {
    int r = p * 4 + tr4;
    dst[(size_t)r * S_ + tc] = (short)f2bf(tile[tc][r]);
  }
}

// ---------------- pipelined GEMM: C = A(MxK) . B(NxK)^T -------------------
// BM=256, BK=64, 8 waves (2M x 4N), double-buffered LDS, counted vmcnt
// (T4: never drain to 0 in loop), XOR 16B-slot swizzle (T2: inverse-swz
// global source + swz read, linear gld_lds dest), setprio MFMA (T5).
// LPT (gld16 per wave per K-tile) = 4 (A) + BN/64 (B).
template<int BN, int KTOT, int BROWS, int LDC, bool GATED>
__global__ __launch_bounds__(512, 2) void gemm_pipe(
    const short* __restrict__ Ag, const short* __restrict__ Bg,
    const float* __restrict__ gate, float* __restrict__ Cg) {
  extern __shared__ char lds[];
  constexpr int NF = BN / 64;              // n-frags per wave (4 or 2)
  constexpr int NT = KTOT / 64;            // K-tiles
  constexpr int ABYTES = 256 * 128;        // 32 KB per A K-tile
  constexpr int BBYTES = BN * 128;
  constexpr int BUFB = ABYTES + BBYTES;

  int wg = blockIdx.x;
  int swz = (wg & 7) * 32 + (wg >> 3);     // 256 wgs -> bijective XCD chunk
  int b = swz >> 6;
  int rem = swz & 63;
  int m0 = (rem >> 3) * 256;
  int n0 = (rem & 7) * BN;

  int tid = threadIdx.x;
  int w = tid >> 6, l = tid & 63;
  int wm = w >> 2, wn = w & 3;

  const short* Ab = Ag + (size_t)b * S_ * KTOT + (size_t)m0 * KTOT;
  const short* Bb = Bg + (size_t)b * BROWS * KTOT + (size_t)n0 * KTOT;

  // staging: lane l covers row srow8 = l>>3 (within 8-row block), 16B chunk
  // (l&7) XOR'd by row&7 (= l>>3) so a linear gld_lds dest + swizzled read
  // compose to identity (rule #21).
  int srow8 = l >> 3;
  int schunk = ((l & 7) ^ srow8) * 8;      // bf16 elem offset in 64-col tile

  // read-side: fragment row, and swizzled 16B slot per k-half
  int arow = wm * 128 + (l & 15);
  int brow = wn * (BN / 4) + (l & 15);
  int hi = l >> 4;                          // 0..3 (k sub-slot)
  int sl0 = (((0 + hi) ^ (l & 7)) * 16);    // kq=0 byte slot
  int sl1 = (((4 + hi) ^ (l & 7)) * 16);    // kq=1 byte slot

  v4f acc[8][NF];
  #pragma unroll
  for (int m = 0; m < 8; ++m)
    #pragma unroll
    for (int n = 0; n < NF; ++n)
      #pragma unroll
      for (int j = 0; j < 4; ++j) acc[m][n][j] = 0.0f;

  auto stage = [&](int t, int buf) {
    char* La = lds + buf * BUFB;
    char* Lb = La + ABYTES;
    const short* As = Ab + (size_t)t * 64 + schunk;
    #pragma unroll
    for (int j = 0; j < 4; ++j) {
      int blk = w * 4 + j;
      gld16(As + (size_t)(blk * 8 + srow8) * KTOT, La + blk * 1024);
    }
    const short* Bs = Bb + (size_t)t * 64 + schunk;
    #pragma unroll
    for (int j = 0; j < NF; ++j) {
      int blk = w * NF + j;
      gld16(Bs + (size_t)(blk * 8 + srow8) * KTOT, Lb + blk * 1024);
    }
  };

  auto compute = [&](int buf) {
    const char* La = lds + buf * BUFB + arow * 128;
    const char* Lb = lds + buf * BUFB + ABYTES + brow * 128;
    s16x8 bf0[NF], bf1[NF];
    #pragma unroll
    for (int n = 0; n < NF; ++n) {
      bf0[n] = *(const s16x8*)(Lb + n * 2048 + sl0);
      bf1[n] = *(const s16x8*)(Lb + n * 2048 + sl1);
    }
    #pragma unroll
    for (int mh = 0; mh < 2; ++mh) {
      s16x8 af[4];
      #pragma unroll
      for (int i = 0; i < 4; ++i)
        af[i] = *(const s16x8*)(La + (mh * 4 + i) * 2048 + sl0);
      __builtin_amdgcn_s_setprio(1);
      #pragma unroll
      for (int i = 0; i < 4; ++i)
        #pragma unroll
        for (int n = 0; n < NF; ++n)
          acc[mh * 4 + i][n] = __builtin_amdgcn_mfma_f32_16x16x32_bf16(
              af[i], bf0[n], acc[mh * 4 + i][n], 0, 0, 0);
      __builtin_amdgcn_s_setprio(0);
      #pragma unroll
      for (int i = 0; i < 4; ++i)
        af[i] = *(const s16x8*)(La + (mh * 4 + i) * 2048 + sl1);
      __builtin_amdgcn_s_setprio(1);
      #pragma unroll
      for (int i = 0; i < 4; ++i)
        #pragma unroll
        for (int n = 0; n < NF; ++n)
          acc[mh * 4 + i][n] = __builtin_amdgcn_mfma_f32_16x16x32_bf16(
              af[i], bf1[n], acc[mh * 4 + i][n], 0, 0, 0);
      __builtin_amdgcn_s_setprio(0);
    }
  };

  stage(0, 0);
  int cur = 0;
  for (int t = 0; t < NT - 1; ++t) {
    stage(t + 1, cur ^ 1);                 // prefetch stays in flight
    if constexpr (BN == 256) { WAITV(8); } else { WAITV(6); }
    barrier_sync();                        // tile t visible to all waves
    compute(cur);
    barrier_sync();                        // all reads of buf[cur] done
    cur ^= 1;
  }
  WAITV(0);
  barrier_sync();
  compute(cur);

  float g = 1.0f;
  if constexpr (GATED) g = gate[b] * 0.03125f;   // sigmoid-gate / sqrt(1024)
  float* Cb = Cg + (size_t)b * S_ * LDC +
              (size_t)(m0 + wm * 128) * LDC + n0 + wn * (BN / 4);
  #pragma unroll
  for (int mf = 0; mf < 8; ++mf)
    #pragma unroll
    for (int n = 0; n < NF; ++n) {
      int r0 = mf * 16 + hi * 4;
      int c = n * 16 + (l & 15);
      #pragma unroll
      for (int j = 0; j < 4; ++j)
        Cb[(size_t)(r0 + j) * LDC + c] = acc[mf][n][j] * g;
    }
}

// ---------------- row softmax: f32 in-place + bf16 copy for PV ------------
__global__ __launch_bounds__(256) void softmax_kernel(
    float* __restrict__ attn, short* __restrict__ attnb) {
  size_t row = blockIdx.x;
  float* p = attn + row * S_;
  int t = threadIdx.x;
  v4f v0 = *(const v4f*)(p + t * 8);
  v4f v1 = *(const v4f*)(p + t * 8 + 4);
  float m = fmaxf(fmaxf(fmaxf(v0[0], v0[1]), fmaxf(v0[2], v0[3])),
                  fmaxf(fmaxf(v1[0], v1[1]), fmaxf(v1[2], v1[3])));
  #pragma unroll
  for (int off = 32; off > 0; off >>= 1) m = fmaxf(m, __shfl_xor(m, off, 64));
  __shared__ float rm[4], rs[4];
  if ((t & 63) == 0) rm[t >> 6] = m;
  __syncthreads();
  m = fmaxf(fmaxf(rm[0], rm[1]), fmaxf(rm[2], rm[3]));
  float e[8]; float sum = 0.0f;
  #pragma unroll
  for (int j = 0; j < 4; ++j) { e[j] = __expf(v0[j] - m); sum += e[j]; }
  #pragma unroll
  for (int j = 0; j < 4; ++j) { e[4 + j] = __expf(v1[j] - m); sum += e[4 + j]; }
  #pragma unroll
  for (int off = 32; off > 0; off >>= 1) sum += __shfl_xor(sum, off, 64);
  if ((t & 63) == 0) rs[t >> 6] = sum;
  __syncthreads();
  sum = rs[0] + rs[1] + rs[2] + rs[3];
  float inv = 1.0f / sum;
  #pragma unroll
  for (int j = 0; j < 4; ++j) v0[j] = e[j] * inv;
  #pragma unroll
  for (int j = 0; j < 4; ++j) v1[j] = e[4 + j] * inv;
  *(v4f*)(p + t * 8) = v0;
  *(v4f*)(p + t * 8 + 4) = v1;
  s16x8 ob;
  ob[0] = (short)f2bf(v0[0]); ob[1] = (short)f2bf(v0[1]);
  ob[2] = (short)f2bf(v0[2]); ob[3] = (short)f2bf(v0[3]);
  ob[4] = (short)f2bf(v1[0]); ob[5] = (short)f2bf(v1[1]);
  ob[6] = (short)f2bf(v1[2]); ob[7] = (short)f2bf(v1[3]);
  *(s16x8*)(attnb + row * S_ + t * 8) = ob;
}

extern "C" void kernel_launch(void* const* d_in, const int* in_sizes, int n_in,
                              void* d_out, int out_size, void* d_ws, size_t ws_size,
                              hipStream_t stream) {
  (void)in_sizes; (void)n_in; (void)out_size; (void)ws_size;
  const float* Q  = (const float*)d_in[0];
  const float* K  = (const float*)d_in[1];
  const float* V  = (const float*)d_in[2];
  const float* tb = (const float*)d_in[3];
  const float* W  = (const float*)d_in[4];
  const float* bias = (const float*)d_in[5];

  float* out  = (float*)d_out;                       // [4,2048,1024]
  float* attn = out + (size_t)B_ * S_ * D_;          // [4,2048,2048]

  char* ws = (char*)d_ws;
  float* gate = (float*)ws;                          // 4 floats
  short* Qb = (short*)(ws + 256);                    // bf16 [4][2048][1024]
  short* Kb = Qb + (size_t)B_ * S_ * D_;             // bf16 [4][2048][1024]
  short* VT = Kb + (size_t)B_ * S_ * D_;             // bf16 [4][1024][2048]
  short* attnb = Qb;                                 // reuse Qb+Kb: bf16 P

  // QK: A=Qb[S][1024], B=Kb[S][1024], C=attn[S][2048], gated
  auto* qkf = gemm_pipe<256, 1024, 2048, 2048, true>;
  // PV: A=attnb[S][2048], B=VT[D][2048], C=out[S][1024]
  auto* pvf = gemm_pipe<128, 2048, 1024, 1024, false>;
  constexpr int QK_LDS = 2 * (256 + 256) * 64 * 2;   // 131072
  constexpr int PV_LDS = 2 * (256 + 128) * 64 * 2;   //  98304
  (void)hipFuncSetAttribute((const void*)qkf,
      hipFuncAttributeMaxDynamicSharedMemorySize, QK_LDS);
  (void)hipFuncSetAttribute((const void*)pvf,
      hipFuncAttributeMaxDynamicSharedMemorySize, PV_LDS);

  gate_kernel<<<1, 256, 0, stream>>>(tb, W, bias, gate);
  cvt_bf16_kernel<<<8192, 256, 0, stream>>>(Q, Qb);
  cvt_bf16_kernel<<<8192, 256, 0, stream>>>(K, Kb);
  vT_kernel<<<dim3(32, 16, 4), 256, 0, stream>>>(V, VT);
  qkf<<<256, 512, QK_LDS, stream>>>(Qb, Kb, gate, attn);
  softmax_kernel<<<8192, 256, 0, stream>>>(attn, attnb);
  pvf<<<256, 512, PV_LDS, stream>>>(attnb, VT, gate, out);
}